// Round 1
// baseline (112.073 us; speedup 1.0000x reference)
//
#include <hip/hip_runtime.h>

// EMA1D straight-through: reference returns state - stop_grad(state) + x,
// whose forward value is exactly x (state - state == 0 for finite state).
// So the kernel is a pure device copy of the input to the output.
// 64*128*8192 fp32 = 256 MiB in + 256 MiB out -> HBM-bound copy.

__global__ __launch_bounds__(256) void ema1d_copy_kernel(
    const float4* __restrict__ in, float4* __restrict__ out, long n4) {
    long i = (long)blockIdx.x * blockDim.x + threadIdx.x;
    long stride = (long)gridDim.x * blockDim.x;
    for (; i < n4; i += stride) {
        out[i] = in[i];
    }
}

extern "C" void kernel_launch(void* const* d_in, const int* in_sizes, int n_in,
                              void* d_out, int out_size, void* d_ws, size_t ws_size,
                              hipStream_t stream) {
    const float* x = (const float*)d_in[0];
    float* out = (float*)d_out;

    long n = (long)out_size;          // 67,108,864 elements, divisible by 4
    long n4 = n / 4;

    int block = 256;
    long want = (n4 + block - 1) / block;
    int grid = (int)(want < 2048 ? want : 2048);   // 256 CUs * 8 blocks/CU cap

    ema1d_copy_kernel<<<grid, block, 0, stream>>>(
        (const float4*)x, (float4*)out, n4);
}